// Round 4
// baseline (12579.692 us; speedup 1.0000x reference)
//
#include <hip/hip_runtime.h>

#define KC 256
#define DIM 64
#define NITER 10

// numpy pairwise sum for 64 elements, inputs already rounded f32:
// r[j] = a[j]+a[j+8]+...+a[j+56] (sequential), then ((r0+r1)+(r2+r3))+((r4+r5)+(r6+r7))
__device__ __forceinline__ float np_pairwise_sq64(const float* a) {
    float r[8];
#pragma unroll
    for (int j = 0; j < 8; ++j) r[j] = __fmul_rn(a[j], a[j]);
#pragma unroll
    for (int i = 8; i < 64; i += 8)
#pragma unroll
        for (int j = 0; j < 8; ++j)
            r[j] = __fadd_rn(r[j], __fmul_rn(a[i + j], a[i + j]));
    float t01 = __fadd_rn(r[0], r[1]), t23 = __fadd_rn(r[2], r[3]);
    float t45 = __fadd_rn(r[4], r[5]), t67 = __fadd_rn(r[6], r[7]);
    return __fadd_rn(__fadd_rn(t01, t23), __fadd_rn(t45, t67));
}

// ---------------- init: c = x[:K] ----------------
__global__ void init_k(const float* __restrict__ x, float* __restrict__ c) {
    const int idx = blockIdx.x * 256 + threadIdx.x;
    if (idx < KC * DIM) c[idx] = x[idx];
}

// ---------------- assign: f32 trajectory-faithful distances ----------------
__global__ __launch_bounds__(256) void assign_k(
    const float* __restrict__ x, const float* __restrict__ c,
    float* __restrict__ labels, int n)
{
    __shared__ float csq[KC];
    // each block recomputes csq (numpy pairwise) — cheap, avoids d_ws
    {
        const int t = threadIdx.x;
        if (t < KC) {
            float cr[DIM];
            const float4* cp = reinterpret_cast<const float4*>(c + t * DIM);
#pragma unroll
            for (int j = 0; j < DIM / 4; ++j) {
                float4 v = cp[j];
                cr[4 * j + 0] = v.x; cr[4 * j + 1] = v.y;
                cr[4 * j + 2] = v.z; cr[4 * j + 3] = v.w;
            }
            csq[t] = np_pairwise_sq64(cr);
        }
    }
    __syncthreads();

    const int i = blockIdx.x * 256 + threadIdx.x;
    if (i >= n) return;

    float xr[DIM];
    const float4* xv = reinterpret_cast<const float4*>(x + (size_t)i * DIM);
#pragma unroll
    for (int j = 0; j < DIM / 4; ++j) {
        float4 v = xv[j];
        xr[4 * j + 0] = v.x; xr[4 * j + 1] = v.y;
        xr[4 * j + 2] = v.z; xr[4 * j + 3] = v.w;
    }
    const float xsq = np_pairwise_sq64(xr);   // matches np.sum(x*x, axis=1)

    float best = __int_as_float(0x7f800000);  // +inf
    int bk = 0;
    int nanIdx = -1;

    for (int k0 = 0; k0 < KC; k0 += 8) {
        float acc[8];
#pragma unroll
        for (int u = 0; u < 8; ++u) acc[u] = 0.0f;
        const float* cp = c + (size_t)k0 * DIM;

        // BLAS-style: per (i,k) single-accumulator FMA chain, ascending d
#pragma unroll
        for (int db = 0; db < DIM / 4; ++db) {
            float4 cv[8];
#pragma unroll
            for (int u = 0; u < 8; ++u)
                cv[u] = *reinterpret_cast<const float4*>(cp + u * DIM + db * 4);
            const float x0 = xr[4 * db + 0], x1 = xr[4 * db + 1];
            const float x2 = xr[4 * db + 2], x3 = xr[4 * db + 3];
#pragma unroll
            for (int u = 0; u < 8; ++u) {
                acc[u] = fmaf(x0, cv[u].x, acc[u]);
                acc[u] = fmaf(x1, cv[u].y, acc[u]);
                acc[u] = fmaf(x2, cv[u].z, acc[u]);
                acc[u] = fmaf(x3, cv[u].w, acc[u]);
            }
        }
#pragma unroll
        for (int u = 0; u < 8; ++u) {
            // d = (x_sq - 2*dot) + c_sq, plain f32 ops, no contraction
            const float dist = __fadd_rn(__fsub_rn(xsq, 2.0f * acc[u]), csq[k0 + u]);
            if (dist < best) { best = dist; bk = k0 + u; }
            if (nanIdx < 0 && dist != dist) nanIdx = k0 + u;  // numpy: first NaN wins
        }
    }
    labels[i] = (float)(nanIdx >= 0 ? nanIdx : bk);
}

// ---------------- reduce: np.add.at semantics — linear f32 chain, ascending i ----------------
__global__ __launch_bounds__(64) void reduce_k(
    const float* __restrict__ x, const float* __restrict__ labels,
    float* __restrict__ c, int n)
{
    const int k = blockIdx.x;        // one block (one wave) per cluster
    const int lane = threadIdx.x;    // owns dimension = lane
    const float fk = (float)k;

    float acc = 0.0f;
    unsigned int cnt = 0;

    const int nch = (n + 255) / 256;
    for (int ch = 0; ch < nch; ++ch) {
        const int base = ch * 256;
        const int i0 = base + lane, i1 = base + 64 + lane;
        const int i2 = base + 128 + lane, i3 = base + 192 + lane;
        const float l0 = (i0 < n) ? labels[i0] : -1.0f;
        const float l1 = (i1 < n) ? labels[i1] : -1.0f;
        const float l2 = (i2 < n) ? labels[i2] : -1.0f;
        const float l3 = (i3 < n) ? labels[i3] : -1.0f;
        unsigned long long m0 = __ballot(l0 == fk);
        unsigned long long m1 = __ballot(l1 == fk);
        unsigned long long m2 = __ballot(l2 == fk);
        unsigned long long m3 = __ballot(l3 == fk);
        cnt += (unsigned int)(__popcll(m0) + __popcll(m1) + __popcll(m2) + __popcll(m3));
        while (m0) { const int j = __builtin_ctzll(m0); m0 &= m0 - 1;
            acc = __fadd_rn(acc, x[(size_t)(base + j) * DIM + lane]); }
        while (m1) { const int j = __builtin_ctzll(m1); m1 &= m1 - 1;
            acc = __fadd_rn(acc, x[(size_t)(base + 64 + j) * DIM + lane]); }
        while (m2) { const int j = __builtin_ctzll(m2); m2 &= m2 - 1;
            acc = __fadd_rn(acc, x[(size_t)(base + 128 + j) * DIM + lane]); }
        while (m3) { const int j = __builtin_ctzll(m3); m3 &= m3 - 1;
            acc = __fadd_rn(acc, x[(size_t)(base + 192 + j) * DIM + lane]); }
    }
    // new_c = sums / Ncl : f32 division; 0/0 -> NaN matches reference
    c[k * DIM + lane] = __fdiv_rn(acc, (float)cnt);
}

extern "C" void kernel_launch(void* const* d_in, const int* in_sizes, int n_in,
                              void* d_out, int out_size, void* d_ws, size_t ws_size,
                              hipStream_t stream)
{
    const float* x = (const float*)d_in[0];
    const int n = in_sizes[0] / DIM;          // 262144

    float* out_c = (float*)d_out;             // [256*64] centroids (working buffer too)
    float* out_labels = out_c + KC * DIM;     // [n] labels as floats

    init_k<<<(KC * DIM + 255) / 256, 256, 0, stream>>>(x, out_c);

    const int assign_nb = (n + 255) / 256;
    for (int it = 0; it < NITER; ++it) {
        assign_k<<<assign_nb, 256, 0, stream>>>(x, out_c, out_labels, n);
        reduce_k<<<KC, 64, 0, stream>>>(x, out_labels, out_c, n);
    }
}

// Round 5
// 4397.730 us; speedup vs baseline: 2.8605x; 2.8605x over previous
//
#include <hip/hip_runtime.h>

#define KC 256
#define DIM 64
#define NITER 10

// numpy pairwise sum for 64 elements, inputs already rounded f32:
// r[j] = a[j]+a[j+8]+...+a[j+56] (sequential), then ((r0+r1)+(r2+r3))+((r4+r5)+(r6+r7))
__device__ __forceinline__ float np_pairwise_sq64(const float* a) {
    float r[8];
#pragma unroll
    for (int j = 0; j < 8; ++j) r[j] = __fmul_rn(a[j], a[j]);
#pragma unroll
    for (int i = 8; i < 64; i += 8)
#pragma unroll
        for (int j = 0; j < 8; ++j)
            r[j] = __fadd_rn(r[j], __fmul_rn(a[i + j], a[i + j]));
    float t01 = __fadd_rn(r[0], r[1]), t23 = __fadd_rn(r[2], r[3]);
    float t45 = __fadd_rn(r[4], r[5]), t67 = __fadd_rn(r[6], r[7]);
    return __fadd_rn(__fadd_rn(t01, t23), __fadd_rn(t45, t67));
}

// ---------------- init: c = x[:K] ----------------
__global__ void init_k(const float* __restrict__ x, float* __restrict__ c) {
    const int idx = blockIdx.x * 256 + threadIdx.x;
    if (idx < KC * DIM) c[idx] = x[idx];
}

// ---------------- assign (+ per-block label histogram) ----------------
__global__ __launch_bounds__(256) void assign_hist_k(
    const float* __restrict__ x, const float* __restrict__ c,
    float* __restrict__ labels, int* __restrict__ hist, int n)
{
    __shared__ float csq[KC];
    __shared__ int whist[4 * KC];
    const int t = threadIdx.x;

    for (int j = t; j < 4 * KC; j += 256) whist[j] = 0;
    if (t < KC) {
        float cr[DIM];
        const float4* cp = reinterpret_cast<const float4*>(c + t * DIM);
#pragma unroll
        for (int j = 0; j < DIM / 4; ++j) {
            float4 v = cp[j];
            cr[4 * j + 0] = v.x; cr[4 * j + 1] = v.y;
            cr[4 * j + 2] = v.z; cr[4 * j + 3] = v.w;
        }
        csq[t] = np_pairwise_sq64(cr);
    }
    __syncthreads();

    const int i = blockIdx.x * 256 + t;
    const bool valid = (i < n);
    int lbl = 0;

    if (valid) {
        float xr[DIM];
        const float4* xv = reinterpret_cast<const float4*>(x + (size_t)i * DIM);
#pragma unroll
        for (int j = 0; j < DIM / 4; ++j) {
            float4 v = xv[j];
            xr[4 * j + 0] = v.x; xr[4 * j + 1] = v.y;
            xr[4 * j + 2] = v.z; xr[4 * j + 3] = v.w;
        }
        const float xsq = np_pairwise_sq64(xr);

        float best = __int_as_float(0x7f800000);
        int bk = 0;
        int nanIdx = -1;

        for (int k0 = 0; k0 < KC; k0 += 8) {
            float acc[8];
#pragma unroll
            for (int u = 0; u < 8; ++u) acc[u] = 0.0f;
            const float* cp = c + (size_t)k0 * DIM;
#pragma unroll
            for (int db = 0; db < DIM / 4; ++db) {
                float4 cv[8];
#pragma unroll
                for (int u = 0; u < 8; ++u)
                    cv[u] = *reinterpret_cast<const float4*>(cp + u * DIM + db * 4);
                const float x0 = xr[4 * db + 0], x1 = xr[4 * db + 1];
                const float x2 = xr[4 * db + 2], x3 = xr[4 * db + 3];
#pragma unroll
                for (int u = 0; u < 8; ++u) {
                    acc[u] = fmaf(x0, cv[u].x, acc[u]);
                    acc[u] = fmaf(x1, cv[u].y, acc[u]);
                    acc[u] = fmaf(x2, cv[u].z, acc[u]);
                    acc[u] = fmaf(x3, cv[u].w, acc[u]);
                }
            }
#pragma unroll
            for (int u = 0; u < 8; ++u) {
                const float dist = __fadd_rn(__fsub_rn(xsq, 2.0f * acc[u]), csq[k0 + u]);
                if (dist < best) { best = dist; bk = k0 + u; }
                if (nanIdx < 0 && dist != dist) nanIdx = k0 + u;  // numpy: first NaN wins
            }
        }
        lbl = (nanIdx >= 0 ? nanIdx : bk);
        labels[i] = (float)lbl;
    }

    // ballot-based per-wave group counts (deterministic)
    const int lane = t & 63, w = t >> 6;
    unsigned long long same = __ballot(valid);
#pragma unroll
    for (int bit = 0; bit < 8; ++bit) {
        unsigned long long bb = __ballot((lbl >> bit) & 1);
        same &= ((lbl >> bit) & 1) ? bb : ~bb;
    }
    if (valid && lane == __builtin_ctzll(same))
        whist[w * KC + lbl] = (int)__popcll(same);
    __syncthreads();
    if (t < KC)
        hist[(size_t)blockIdx.x * KC + t] =
            whist[t] + whist[KC + t] + whist[2 * KC + t] + whist[3 * KC + t];
}

// ---------------- scan: exclusive prefix over blocks per cluster + bases ----------------
__global__ __launch_bounds__(256) void scan_k(
    int* __restrict__ hist, int nb, int* __restrict__ base, int* __restrict__ cnt)
{
    __shared__ int tot[KC];
    __shared__ int bs[KC];
    const int k = threadIdx.x;
    int s = 0;
#pragma unroll 8
    for (int b = 0; b < nb; ++b) {
        const int v = hist[(size_t)b * KC + k];
        hist[(size_t)b * KC + k] = s;
        s += v;
    }
    tot[k] = s;
    __syncthreads();
    if (k == 0) {
        int a = 0;
        for (int j = 0; j < KC; ++j) { bs[j] = a; a += tot[j]; }
    }
    __syncthreads();
    base[k] = bs[k];
    cnt[k] = tot[k];
}

// ---------------- scatter: stable counting-sort placement ----------------
__global__ __launch_bounds__(256) void scatter_k(
    const float* __restrict__ labels, const int* __restrict__ hist,
    const int* __restrict__ base, int* __restrict__ order, int n)
{
    __shared__ int whist[4 * KC];
    const int t = threadIdx.x;
    for (int j = t; j < 4 * KC; j += 256) whist[j] = 0;
    __syncthreads();

    const int i = blockIdx.x * 256 + t;
    const bool valid = (i < n);
    const int lbl = valid ? (int)labels[i] : 0;
    const int lane = t & 63, w = t >> 6;

    unsigned long long same = __ballot(valid);
#pragma unroll
    for (int bit = 0; bit < 8; ++bit) {
        unsigned long long bb = __ballot((lbl >> bit) & 1);
        same &= ((lbl >> bit) & 1) ? bb : ~bb;
    }
    const unsigned long long below = (1ull << lane) - 1ull;
    const int rank_wave = (int)__popcll(same & below);
    if (valid && lane == __builtin_ctzll(same))
        whist[w * KC + lbl] = (int)__popcll(same);
    __syncthreads();

    if (valid) {
        int off = rank_wave;
        for (int ww = 0; ww < w; ++ww) off += whist[ww * KC + lbl];
        const int pos = base[lbl] + hist[(size_t)blockIdx.x * KC + lbl] + off;
        order[pos] = i;
    }
}

// ---------------- gather: sequential f32 chain per (cluster, dim), pipelined ----------------
__global__ __launch_bounds__(64) void gather_k(
    const float* __restrict__ x, const int* __restrict__ order,
    const int* __restrict__ base, const int* __restrict__ cnt,
    float* __restrict__ c)
{
    const int k = blockIdx.x;
    const int lane = threadIdx.x;
    const int b0 = base[k];
    const int ct = cnt[k];

    float acc = 0.0f;
    int j = 0;
    for (; j + 32 <= ct; j += 32) {
        float v[32];
#pragma unroll
        for (int u = 0; u < 32; ++u) {
            const int idx = order[b0 + j + u];
            v[u] = x[(size_t)idx * DIM + lane];
        }
#pragma unroll
        for (int u = 0; u < 32; ++u) acc = __fadd_rn(acc, v[u]);
    }
    for (; j < ct; ++j) {
        const int idx = order[b0 + j];
        acc = __fadd_rn(acc, x[(size_t)idx * DIM + lane]);
    }
    c[k * DIM + lane] = __fdiv_rn(acc, (float)ct);   // 0/0 -> NaN matches ref
}

// ---------------- fallback reduce (round-4, used only if d_ws too small) ----------------
__global__ __launch_bounds__(64) void reduce_k(
    const float* __restrict__ x, const float* __restrict__ labels,
    float* __restrict__ c, int n)
{
    const int k = blockIdx.x;
    const int lane = threadIdx.x;
    const float fk = (float)k;
    float acc = 0.0f;
    unsigned int cntv = 0;
    const int nch = (n + 255) / 256;
    for (int ch = 0; ch < nch; ++ch) {
        const int bbase = ch * 256;
        unsigned long long m[4];
        unsigned int cadd = 0;
#pragma unroll
        for (int q = 0; q < 4; ++q) {
            const int ii = bbase + q * 64 + lane;
            const float l = (ii < n) ? labels[ii] : -1.0f;
            m[q] = __ballot(l == fk);
            cadd += (unsigned int)__popcll(m[q]);
        }
        cntv += cadd;
#pragma unroll
        for (int q = 0; q < 4; ++q) {
            unsigned long long mm = m[q];
            while (mm) {
                const int jj = __builtin_ctzll(mm);
                mm &= mm - 1;
                acc = __fadd_rn(acc, x[(size_t)(bbase + q * 64 + jj) * DIM + lane]);
            }
        }
    }
    c[k * DIM + lane] = __fdiv_rn(acc, (float)cntv);
}

extern "C" void kernel_launch(void* const* d_in, const int* in_sizes, int n_in,
                              void* d_out, int out_size, void* d_ws, size_t ws_size,
                              hipStream_t stream)
{
    const float* x = (const float*)d_in[0];
    const int n = in_sizes[0] / DIM;          // 262144

    float* out_c = (float*)d_out;             // [256*64] centroids (working buffer too)
    float* out_labels = out_c + KC * DIM;     // [n] labels as floats

    const int nb = (n + 255) / 256;           // 1024 blocks of 256 points

    // workspace layout for fast path
    char* p = (char*)d_ws;
    int* hist  = (int*)p;  p += (size_t)nb * KC * sizeof(int);   // 1 MiB
    int* order = (int*)p;  p += (size_t)n * sizeof(int);         // 1 MiB
    int* base  = (int*)p;  p += KC * sizeof(int);
    int* cnt   = (int*)p;  p += KC * sizeof(int);
    const size_t needed = (size_t)(p - (char*)d_ws);
    const bool fast = (ws_size >= needed);

    init_k<<<(KC * DIM + 255) / 256, 256, 0, stream>>>(x, out_c);

    for (int it = 0; it < NITER; ++it) {
        if (fast) {
            assign_hist_k<<<nb, 256, 0, stream>>>(x, out_c, out_labels, hist, n);
            scan_k<<<1, 256, 0, stream>>>(hist, nb, base, cnt);
            scatter_k<<<nb, 256, 0, stream>>>(out_labels, hist, base, order, n);
            gather_k<<<KC, 64, 0, stream>>>(x, order, base, cnt, out_c);
        } else {
            assign_hist_k<<<nb, 256, 0, stream>>>(x, out_c, out_labels, (int*)d_ws, n);
            // note: fallback still needs hist buffer target; reuse d_ws head if any,
            // otherwise labels-only reduce path below ignores hist entirely.
            reduce_k<<<KC, 64, 0, stream>>>(x, out_labels, out_c, n);
        }
    }
}

// Round 6
// 4072.052 us; speedup vs baseline: 3.0893x; 1.0800x over previous
//
#include <hip/hip_runtime.h>

#define KC 256
#define DIM 64
#define NITER 10

// numpy pairwise sum for 64 elements, inputs already rounded f32:
// r[j] = a[j]+a[j+8]+...+a[j+56] (sequential), then ((r0+r1)+(r2+r3))+((r4+r5)+(r6+r7))
__device__ __forceinline__ float np_pairwise_sq64(const float* a) {
    float r[8];
#pragma unroll
    for (int j = 0; j < 8; ++j) r[j] = __fmul_rn(a[j], a[j]);
#pragma unroll
    for (int i = 8; i < 64; i += 8)
#pragma unroll
        for (int j = 0; j < 8; ++j)
            r[j] = __fadd_rn(r[j], __fmul_rn(a[i + j], a[i + j]));
    float t01 = __fadd_rn(r[0], r[1]), t23 = __fadd_rn(r[2], r[3]);
    float t45 = __fadd_rn(r[4], r[5]), t67 = __fadd_rn(r[6], r[7]);
    return __fadd_rn(__fadd_rn(t01, t23), __fadd_rn(t45, t67));
}

// ---------------- init: c = x[:K] ----------------
__global__ void init_k(const float* __restrict__ x, float* __restrict__ c) {
    const int idx = blockIdx.x * 256 + threadIdx.x;
    if (idx < KC * DIM) c[idx] = x[idx];
}

// ---------------- assign (+ per-block label histogram) ----------------
__global__ __launch_bounds__(256) void assign_hist_k(
    const float* __restrict__ x, const float* __restrict__ c,
    float* __restrict__ labels, int* __restrict__ hist, int n)
{
    __shared__ float csq[KC];
    __shared__ int whist[4 * KC];
    const int t = threadIdx.x;

    for (int j = t; j < 4 * KC; j += 256) whist[j] = 0;
    if (t < KC) {
        float cr[DIM];
        const float4* cp = reinterpret_cast<const float4*>(c + t * DIM);
#pragma unroll
        for (int j = 0; j < DIM / 4; ++j) {
            float4 v = cp[j];
            cr[4 * j + 0] = v.x; cr[4 * j + 1] = v.y;
            cr[4 * j + 2] = v.z; cr[4 * j + 3] = v.w;
        }
        csq[t] = np_pairwise_sq64(cr);
    }
    __syncthreads();

    const int i = blockIdx.x * 256 + t;
    const bool valid = (i < n);
    int lbl = 0;

    if (valid) {
        float xr[DIM];
        const float4* xv = reinterpret_cast<const float4*>(x + (size_t)i * DIM);
#pragma unroll
        for (int j = 0; j < DIM / 4; ++j) {
            float4 v = xv[j];
            xr[4 * j + 0] = v.x; xr[4 * j + 1] = v.y;
            xr[4 * j + 2] = v.z; xr[4 * j + 3] = v.w;
        }
        const float xsq = np_pairwise_sq64(xr);

        float best = __int_as_float(0x7f800000);
        int bk = 0;
        int nanIdx = -1;

        for (int k0 = 0; k0 < KC; k0 += 8) {
            float acc[8];
#pragma unroll
            for (int u = 0; u < 8; ++u) acc[u] = 0.0f;
            const float* cp = c + (size_t)k0 * DIM;
#pragma unroll
            for (int db = 0; db < DIM / 4; ++db) {
                float4 cv[8];
#pragma unroll
                for (int u = 0; u < 8; ++u)
                    cv[u] = *reinterpret_cast<const float4*>(cp + u * DIM + db * 4);
                const float x0 = xr[4 * db + 0], x1 = xr[4 * db + 1];
                const float x2 = xr[4 * db + 2], x3 = xr[4 * db + 3];
#pragma unroll
                for (int u = 0; u < 8; ++u) {
                    acc[u] = fmaf(x0, cv[u].x, acc[u]);
                    acc[u] = fmaf(x1, cv[u].y, acc[u]);
                    acc[u] = fmaf(x2, cv[u].z, acc[u]);
                    acc[u] = fmaf(x3, cv[u].w, acc[u]);
                }
            }
#pragma unroll
            for (int u = 0; u < 8; ++u) {
                const float dist = __fadd_rn(__fsub_rn(xsq, 2.0f * acc[u]), csq[k0 + u]);
                if (dist < best) { best = dist; bk = k0 + u; }
                if (nanIdx < 0 && dist != dist) nanIdx = k0 + u;  // numpy: first NaN wins
            }
        }
        lbl = (nanIdx >= 0 ? nanIdx : bk);
        labels[i] = (float)lbl;
    }

    // ballot-based per-wave group counts (deterministic)
    const int lane = t & 63, w = t >> 6;
    unsigned long long same = __ballot(valid);
#pragma unroll
    for (int bit = 0; bit < 8; ++bit) {
        unsigned long long bb = __ballot((lbl >> bit) & 1);
        same &= ((lbl >> bit) & 1) ? bb : ~bb;
    }
    if (valid && lane == __builtin_ctzll(same))
        whist[w * KC + lbl] = (int)__popcll(same);
    __syncthreads();
    if (t < KC)
        hist[(size_t)blockIdx.x * KC + t] =
            whist[t] + whist[KC + t] + whist[2 * KC + t] + whist[3 * KC + t];
}

// ---------------- scan: exclusive prefix over blocks + 16B-aligned cluster bases ----------------
__global__ __launch_bounds__(256) void scan_k(
    int* __restrict__ hist, int nb, int* __restrict__ base, int* __restrict__ cnt)
{
    __shared__ int tot[KC];
    __shared__ int bs[KC];
    const int k = threadIdx.x;
    int s = 0;
#pragma unroll 8
    for (int b = 0; b < nb; ++b) {
        const int v = hist[(size_t)b * KC + k];
        hist[(size_t)b * KC + k] = s;
        s += v;
    }
    tot[k] = s;
    __syncthreads();
    if (k == 0) {
        int a = 0;
        for (int j = 0; j < KC; ++j) { bs[j] = a; a += (tot[j] + 3) & ~3; }  // 4-elt aligned segments
    }
    __syncthreads();
    base[k] = bs[k];
    cnt[k] = tot[k];
}

// ---------------- scatter: stable counting-sort placement (into padded segments) ----------------
__global__ __launch_bounds__(256) void scatter_k(
    const float* __restrict__ labels, const int* __restrict__ hist,
    const int* __restrict__ base, int* __restrict__ order, int n)
{
    __shared__ int whist[4 * KC];
    const int t = threadIdx.x;
    for (int j = t; j < 4 * KC; j += 256) whist[j] = 0;
    __syncthreads();

    const int i = blockIdx.x * 256 + t;
    const bool valid = (i < n);
    const int lbl = valid ? (int)labels[i] : 0;
    const int lane = t & 63, w = t >> 6;

    unsigned long long same = __ballot(valid);
#pragma unroll
    for (int bit = 0; bit < 8; ++bit) {
        unsigned long long bb = __ballot((lbl >> bit) & 1);
        same &= ((lbl >> bit) & 1) ? bb : ~bb;
    }
    const unsigned long long below = (1ull << lane) - 1ull;
    const int rank_wave = (int)__popcll(same & below);
    if (valid && lane == __builtin_ctzll(same))
        whist[w * KC + lbl] = (int)__popcll(same);
    __syncthreads();

    if (valid) {
        int off = rank_wave;
        for (int ww = 0; ww < w; ++ww) off += whist[ww * KC + lbl];
        const int pos = base[lbl] + hist[(size_t)blockIdx.x * KC + lbl] + off;
        order[pos] = i;
    }
}

// ---------------- permute + transpose: buf[d][pos] = x[order[pos]][d] ----------------
__global__ __launch_bounds__(256) void transpose_k(
    const float* __restrict__ x, const int* __restrict__ order,
    float* __restrict__ buf, int nstride)
{
    __shared__ float tile[64][65];
    __shared__ int idxs[64];
    const int t = threadIdx.x;
    const int p0 = blockIdx.x * 64;
    if (t < 64) idxs[t] = order[p0 + t];
    __syncthreads();
    const int w = t >> 6, lane = t & 63;
#pragma unroll
    for (int r = 0; r < 16; ++r) {
        const int row = w * 16 + r;
        tile[row][lane] = x[(size_t)idxs[row] * DIM + lane];   // coalesced 256B row read
    }
    __syncthreads();
#pragma unroll
    for (int r = 0; r < 16; ++r) {
        const int d = w * 16 + r;
        buf[(size_t)d * nstride + p0 + lane] = tile[lane][d];  // coalesced 256B write
    }
}

// ---------------- sum: contiguous float4 streams, exact ascending-order f32 chain ----------------
__global__ __launch_bounds__(64) void sum_k(
    const float* __restrict__ buf, const int* __restrict__ base,
    const int* __restrict__ cnt, float* __restrict__ c, int nstride)
{
    const int k = blockIdx.x;
    const int lane = threadIdx.x;          // = dim
    const int b0 = base[k];                // multiple of 4 -> 16B aligned
    const int ct = cnt[k];
    const float* s = buf + (size_t)lane * nstride + b0;

    float acc = 0.0f;
    int j = 0;
    const int ct4 = ct & ~3;
    for (; j + 32 <= ct4; j += 32) {
        float4 v[8];
#pragma unroll
        for (int u = 0; u < 8; ++u)
            v[u] = *reinterpret_cast<const float4*>(s + j + 4 * u);  // 8 loads in flight
#pragma unroll
        for (int u = 0; u < 8; ++u) {
            acc = __fadd_rn(acc, v[u].x); acc = __fadd_rn(acc, v[u].y);
            acc = __fadd_rn(acc, v[u].z); acc = __fadd_rn(acc, v[u].w);
        }
    }
    for (; j + 4 <= ct4; j += 4) {
        float4 v = *reinterpret_cast<const float4*>(s + j);
        acc = __fadd_rn(acc, v.x); acc = __fadd_rn(acc, v.y);
        acc = __fadd_rn(acc, v.z); acc = __fadd_rn(acc, v.w);
    }
    for (; j < ct; ++j) acc = __fadd_rn(acc, s[j]);

    c[k * DIM + lane] = __fdiv_rn(acc, (float)ct);   // 0/0 -> NaN matches ref
}

// ---------------- fallback gather (round-5 proven) ----------------
__global__ __launch_bounds__(64) void gather_k(
    const float* __restrict__ x, const int* __restrict__ order,
    const int* __restrict__ base, const int* __restrict__ cnt,
    float* __restrict__ c)
{
    const int k = blockIdx.x;
    const int lane = threadIdx.x;
    const int b0 = base[k];
    const int ct = cnt[k];
    float acc = 0.0f;
    int j = 0;
    for (; j + 32 <= ct; j += 32) {
        float v[32];
#pragma unroll
        for (int u = 0; u < 32; ++u)
            v[u] = x[(size_t)order[b0 + j + u] * DIM + lane];
#pragma unroll
        for (int u = 0; u < 32; ++u) acc = __fadd_rn(acc, v[u]);
    }
    for (; j < ct; ++j)
        acc = __fadd_rn(acc, x[(size_t)order[b0 + j] * DIM + lane]);
    c[k * DIM + lane] = __fdiv_rn(acc, (float)ct);
}

extern "C" void kernel_launch(void* const* d_in, const int* in_sizes, int n_in,
                              void* d_out, int out_size, void* d_ws, size_t ws_size,
                              hipStream_t stream)
{
    const float* x = (const float*)d_in[0];
    const int n = in_sizes[0] / DIM;          // 262144

    float* out_c = (float*)d_out;             // [256*64] centroids (working buffer too)
    float* out_labels = out_c + KC * DIM;     // [n] labels as floats

    const int nb = (n + 255) / 256;           // 1024
    const int nstride = n + 1024;             // padded sorted-position stride

    // workspace layout (256B-aligned blocks)
    size_t off = 0;
    auto alloc = [&](size_t bytes) -> size_t {
        size_t o = off; off = (off + bytes + 255) & ~(size_t)255; return o;
    };
    char* w = (char*)d_ws;
    int*   hist  = (int*)(w + alloc((size_t)nb * KC * sizeof(int)));
    int*   base  = (int*)(w + alloc(KC * sizeof(int)));
    int*   cnt   = (int*)(w + alloc(KC * sizeof(int)));
    int*   order = (int*)(w + alloc((size_t)nstride * sizeof(int)));
    const size_t med_need = off;
    float* buf   = (float*)(w + alloc((size_t)DIM * nstride * sizeof(float)));
    const size_t big_need = off;

    const bool big = (ws_size >= big_need);
    const bool med = (ws_size >= med_need);

    init_k<<<(KC * DIM + 255) / 256, 256, 0, stream>>>(x, out_c);
    if (big)  // pad slots of order must hold valid indices before first transpose
        hipMemsetAsync(order, 0, (size_t)nstride * sizeof(int), stream);

    for (int it = 0; it < NITER; ++it) {
        assign_hist_k<<<nb, 256, 0, stream>>>(x, out_c, out_labels, hist, n);
        if (med) {
            scan_k<<<1, 256, 0, stream>>>(hist, nb, base, cnt);
            scatter_k<<<nb, 256, 0, stream>>>(out_labels, hist, base, order, n);
            if (big) {
                transpose_k<<<nstride / 64, 256, 0, stream>>>(x, order, buf, nstride);
                sum_k<<<KC, 64, 0, stream>>>(buf, base, cnt, out_c, nstride);
            } else {
                gather_k<<<KC, 64, 0, stream>>>(x, order, base, cnt, out_c);
            }
        }
    }
}